// Round 1
// baseline (6650.842 us; speedup 1.0000x reference)
//
#include <hip/hip_runtime.h>

typedef float  f4v __attribute__((ext_vector_type(4)));
typedef short  s8v __attribute__((ext_vector_type(8)));

#define B_   64
#define L_   128
#define H_   1024
#define E_   1024
#define BL_  8192           // B*L
#define T_   255
#define RMAX 127

__device__ __forceinline__ unsigned short f2bf(float f) {
    union { float f; unsigned int u; } v; v.f = f;
    unsigned int u = v.u;
    unsigned int r = u + 0x7fffu + ((u >> 16) & 1u);
    return (unsigned short)(r >> 16);
}
__device__ __forceinline__ float bf2f(unsigned short s) {
    union { unsigned int u; float f; } v; v.u = ((unsigned int)s) << 16;
    return v.f;
}
__device__ __forceinline__ float sigf(float x) { return 1.f / (1.f + expf(-x)); }

// ---------------- conversion kernels ----------------
__global__ void k_cvt_bf16(const float* __restrict__ in, unsigned short* __restrict__ out, long n4) {
    long i = blockIdx.x * (long)blockDim.x + threadIdx.x;
    if (i >= n4) return;
    float4 v = ((const float4*)in)[i];
    ushort4 o;
    o.x = f2bf(v.x); o.y = f2bf(v.y); o.z = f2bf(v.z); o.w = f2bf(v.w);
    ((ushort4*)out)[i] = o;
}

// in [K][N] fp32 -> out [N][K] bf16
__global__ void k_transpose_bf16(const float* __restrict__ in, unsigned short* __restrict__ out, int K, int N) {
    __shared__ float tile[32][33];
    int n0 = blockIdx.x * 32, k0 = blockIdx.y * 32;
    int tx = threadIdx.x, ty = threadIdx.y;   // 32 x 8
    for (int i = ty; i < 32; i += 8) tile[i][tx] = in[(size_t)(k0 + i) * N + n0 + tx];
    __syncthreads();
    for (int i = ty; i < 32; i += 8) out[(size_t)(n0 + i) * K + k0 + tx] = f2bf(tile[tx][i]);
}

// ---------------- control: simulate uniform stack machine ----------------
// desc[0] = n_red; desc[1] = final src; desc[2+r] = left src; desc[2+RMAX+r] = right src
// src encoding: >=0 word position; <0 node (-1-r)
__global__ void k_control(const int* __restrict__ tr, int* __restrict__ desc) {
    if (threadIdx.x != 0 || blockIdx.x != 0) return;
    int stack[140];
    int sp = 0, bp = 0, r = 0;
    for (int t = 0; t < T_; ++t) {
        int a = tr[t];                         // row 0 of [B,T] (uniform batch)
        if (a == 1) {                          // SHIFT
            if (bp < L_) { stack[sp++] = bp; bp++; }
        } else if (a == 2) {                   // REDUCE
            if (sp >= 2) {
                int right = stack[sp - 1], left = stack[sp - 2];
                sp -= 2;
                desc[2 + r] = left;
                desc[2 + RMAX + r] = right;
                stack[sp++] = -(r + 1);
                r++;
            }
        }
    }
    desc[0] = r;
    desc[1] = (sp > 0) ? stack[sp - 1] : 0;
}

// ---------------- word projection GEMM ----------------
// sb [8192][1024] bf16 @ Wwt[n][k] bf16 -> hw bf16 [8192][1024] (cols<1024), cw f32 (cols>=1024)
__global__ __launch_bounds__(256) void k_proj(const unsigned short* __restrict__ sb,
                                              const unsigned short* __restrict__ wwt,
                                              const float* __restrict__ bw,
                                              unsigned short* __restrict__ hw,
                                              float* __restrict__ cw) {
    int w = threadIdx.x >> 6, lane = threadIdx.x & 63;
    int ct = blockIdx.x, rt = blockIdx.y;      // 8 col-tiles x 128 row-tiles
    int rowbase = rt * 64 + w * 16;
    int n0 = ct * 256;
    int lr = lane & 15, lk = (lane >> 4) * 8;
    f4v acc[16];
    #pragma unroll
    for (int t = 0; t < 16; ++t) acc[t] = (f4v){0.f, 0.f, 0.f, 0.f};
    const unsigned short* arow = sb + (size_t)(rowbase + lr) * 1024 + lk;
    for (int kk = 0; kk < 1024; kk += 32) {
        s8v a = *(const s8v*)(arow + kk);
        #pragma unroll
        for (int t = 0; t < 16; ++t) {
            s8v b = *(const s8v*)(wwt + (size_t)(n0 + t * 16 + lr) * 1024 + kk + lk);
            acc[t] = __builtin_amdgcn_mfma_f32_16x16x32_bf16(a, b, acc[t], 0, 0, 0);
        }
    }
    int rj = (lane >> 4) * 4;
    #pragma unroll
    for (int t = 0; t < 16; ++t) {
        int col = n0 + t * 16 + lr;
        float bias = bw[col];
        #pragma unroll
        for (int j = 0; j < 4; ++j) {
            int m = rowbase + rj + j;
            float v = acc[t][j] + bias;
            if (col < H_) hw[(size_t)m * H_ + col] = f2bf(v);
            else          cw[(size_t)m * H_ + (col - H_)] = v;
        }
    }
}

// ---------------- one sequential reduce step ----------------
// A = [lh | rh] gathered (64 x 2048 bf16), B = Wrt[n][k] (5120 x 2048), fused gates.
__global__ __launch_bounds__(256) void k_reduce(const int* __restrict__ desc,
                                                const unsigned short* __restrict__ hw,
                                                const float* __restrict__ cw,
                                                const unsigned short* __restrict__ wrt,
                                                const float* __restrict__ br,
                                                unsigned short* __restrict__ nhb,
                                                float* __restrict__ nhf,
                                                float* __restrict__ nc,
                                                int r) {
    if (r >= desc[0]) return;
    int ls = desc[2 + r], rs = desc[2 + RMAX + r];
    int w = threadIdx.x >> 6, lane = threadIdx.x & 63;
    int b = blockIdx.x;                       // 64 blocks x 16 H-cols
    int lr = lane & 15, lk = (lane >> 4) * 8;
    int arow = w * 16 + lr;                   // batch row this lane feeds to A
    const unsigned short* lbase = (ls >= 0)
        ? hw  + ((size_t)(arow * L_ + ls) << 10)
        : nhb + ((size_t)((-1 - ls) * B_ + arow) << 10);
    const unsigned short* rbase = (rs >= 0)
        ? hw  + ((size_t)(arow * L_ + rs) << 10)
        : nhb + ((size_t)((-1 - rs) * B_ + arow) << 10);
    f4v acc[5];
    #pragma unroll
    for (int g = 0; g < 5; ++g) acc[g] = (f4v){0.f, 0.f, 0.f, 0.f};
    for (int kk = 0; kk < 2048; kk += 32) {
        const unsigned short* src = (kk < 1024) ? (lbase + kk) : (rbase + (kk - 1024));
        s8v a = *(const s8v*)(src + lk);
        #pragma unroll
        for (int g = 0; g < 5; ++g) {
            int col = g * 1024 + b * 16 + lr;
            s8v bb = *(const s8v*)(wrt + (size_t)col * 2048 + kk + lk);
            acc[g] = __builtin_amdgcn_mfma_f32_16x16x32_bf16(a, bb, acc[g], 0, 0, 0);
        }
    }
    int ch = b * 16 + lr;
    float bi  = br[ch];
    float bfl = br[1024 + ch];
    float bfr = br[2048 + ch];
    float bo  = br[3072 + ch];
    float bg  = br[4096 + ch];
    #pragma unroll
    for (int j = 0; j < 4; ++j) {
        int m = w * 16 + (lane >> 4) * 4 + j;
        float iv  = acc[0][j] + bi;
        float flv = acc[1][j] + bfl;
        float frv = acc[2][j] + bfr;
        float ov  = acc[3][j] + bo;
        float gv  = acc[4][j] + bg;
        float lc = (ls >= 0) ? cw[(size_t)(m * L_ + ls) * H_ + ch]
                             : nc[(size_t)((-1 - ls) * B_ + m) * H_ + ch];
        float rc = (rs >= 0) ? cw[(size_t)(m * L_ + rs) * H_ + ch]
                             : nc[(size_t)((-1 - rs) * B_ + m) * H_ + ch];
        float cn = sigf(flv) * lc + sigf(frv) * rc + sigf(iv) * tanhf(gv);
        float hn = sigf(ov) * tanhf(cn);
        size_t o = (size_t)(r * B_ + m) * H_ + ch;
        nc[o] = cn;
        nhf[o] = hn;
        nhb[o] = f2bf(hn);
    }
}

// ---------------- final output ----------------
__global__ void k_final(const int* __restrict__ desc,
                        const unsigned short* __restrict__ hw,
                        const float* __restrict__ nhf,
                        float* __restrict__ out) {
    int idx = blockIdx.x * 256 + threadIdx.x;
    if (idx >= B_ * H_) return;
    int m = idx >> 10, ch = idx & 1023;
    int fs = desc[1];
    float v;
    if (fs >= 0) v = bf2f(hw[(size_t)(m * L_ + fs) * H_ + ch]);
    else         v = nhf[(size_t)((-1 - fs) * B_ + m) * H_ + ch];
    out[idx] = v;
}

extern "C" void kernel_launch(void* const* d_in, const int* in_sizes, int n_in,
                              void* d_out, int out_size, void* d_ws, size_t ws_size,
                              hipStream_t stream) {
    const float* sentence = (const float*)d_in[0];
    const int*   trans    = (const int*)d_in[1];
    const float* Ww       = (const float*)d_in[2];
    const float* bw       = (const float*)d_in[3];
    const float* Wr       = (const float*)d_in[4];
    const float* br       = (const float*)d_in[5];
    float* out = (float*)d_out;

    char* w = (char*)d_ws;
    size_t off = 0;
    unsigned short* Wrt = (unsigned short*)(w + off); off += (size_t)5120 * 2048 * 2;  // 21.0 MB
    unsigned short* Wwt = (unsigned short*)(w + off); off += (size_t)2048 * 1024 * 2;  //  4.2 MB
    unsigned short* sb  = (unsigned short*)(w + off); off += (size_t)BL_ * 1024 * 2;   // 16.8 MB
    unsigned short* hw  = (unsigned short*)(w + off); off += (size_t)BL_ * 1024 * 2;   // 16.8 MB
    float*          cw  = (float*)(w + off);          off += (size_t)BL_ * 1024 * 4;   // 33.6 MB
    unsigned short* nhb = (unsigned short*)(w + off); off += (size_t)RMAX * B_ * 1024 * 2; // 16.6 MB
    float*          nhf = (float*)(w + off);          off += (size_t)RMAX * B_ * 1024 * 4; // 33.3 MB
    float*          nc  = (float*)(w + off);          off += (size_t)RMAX * B_ * 1024 * 4; // 33.3 MB
    int*            desc = (int*)(w + off);           off += 1024;

    // sentence fp32 -> bf16
    {
        long n4 = (long)BL_ * 1024 / 4;
        k_cvt_bf16<<<dim3((unsigned)((n4 + 255) / 256)), dim3(256), 0, stream>>>(sentence, sb, n4);
    }
    // Ww [1024][2048] -> Wwt [2048][1024] bf16
    k_transpose_bf16<<<dim3(2048 / 32, 1024 / 32), dim3(32, 8), 0, stream>>>(Ww, Wwt, 1024, 2048);
    // Wr [2048][5120] -> Wrt [5120][2048] bf16
    k_transpose_bf16<<<dim3(5120 / 32, 2048 / 32), dim3(32, 8), 0, stream>>>(Wr, Wrt, 2048, 5120);
    // control
    k_control<<<dim3(1), dim3(1), 0, stream>>>(trans, desc);
    // word projection
    k_proj<<<dim3(8, 128), dim3(256), 0, stream>>>(sb, Wwt, bw, hw, cw);
    // sequential reduces
    for (int r = 0; r < RMAX; ++r)
        k_reduce<<<dim3(64), dim3(256), 0, stream>>>(desc, hw, cw, Wrt, br, nhb, nhf, nc, r);
    // final
    k_final<<<dim3((B_ * H_ + 255) / 256), dim3(256), 0, stream>>>(desc, hw, nhf, out);
}

// Round 2
// 2109.376 us; speedup vs baseline: 3.1530x; 3.1530x over previous
//
#include <hip/hip_runtime.h>

typedef float  f4v __attribute__((ext_vector_type(4)));
typedef short  s8v __attribute__((ext_vector_type(8)));

#define B_   64
#define L_   128
#define H_   1024
#define T_   255
#define RMAX 127
#define KC   512

__device__ __forceinline__ unsigned short f2bf(float f) {
    union { float f; unsigned int u; } v; v.f = f;
    unsigned int u = v.u;
    unsigned int r = u + 0x7fffu + ((u >> 16) & 1u);
    return (unsigned short)(r >> 16);
}
__device__ __forceinline__ float bf2f(unsigned short s) {
    union { unsigned int u; float f; } v; v.u = ((unsigned int)s) << 16;
    return v.f;
}
__device__ __forceinline__ float sigf(float x) { return 1.f / (1.f + expf(-x)); }

// ---------------- conversion ----------------
__global__ void k_cvt_bf16(const float* __restrict__ in, unsigned short* __restrict__ out, long n4) {
    long i = blockIdx.x * (long)blockDim.x + threadIdx.x;
    if (i >= n4) return;
    float4 v = ((const float4*)in)[i];
    ushort4 o;
    o.x = f2bf(v.x); o.y = f2bf(v.y); o.z = f2bf(v.z); o.w = f2bf(v.w);
    ((ushort4*)out)[i] = o;
}

// in [K][N] fp32 -> out [N][K] bf16
__global__ void k_transpose_bf16(const float* __restrict__ in, unsigned short* __restrict__ out, int K, int N) {
    __shared__ float tile[32][33];
    int n0 = blockIdx.x * 32, k0 = blockIdx.y * 32;
    int tx = threadIdx.x, ty = threadIdx.y;   // 32 x 8
    for (int i = ty; i < 32; i += 8) tile[i][tx] = in[(size_t)(k0 + i) * N + n0 + tx];
    __syncthreads();
    for (int i = ty; i < 32; i += 8) out[(size_t)(n0 + i) * K + k0 + tx] = f2bf(tile[tx][i]);
}

// Pre-pack Wrt[n][k] into per-block, per-chunk, LDS-swizzled contiguous layout.
// unit u = ((bid*4 + c)*80 + cc)*64 + kgs ; kg = kgs ^ (cc&7)
__global__ void k_pack_wr(const unsigned short* __restrict__ wrt, unsigned short* __restrict__ wrtb) {
    int u = blockIdx.x * 256 + threadIdx.x;           // [0, 64*4*80*64)
    int kgs = u & 63;
    int cc  = (u >> 6) % 80;
    int c   = ((u >> 6) / 80) % 4;
    int bid = (u >> 6) / 320;
    int kg  = kgs ^ (cc & 7);
    int g = cc >> 4, ci = cc & 15;
    int gcol = g * 1024 + bid * 16 + ci;
    int k = c * KC + kg * 8;
    s8v v = *(const s8v*)(wrt + (size_t)gcol * 2048 + k);
    *(s8v*)(wrtb + (size_t)u * 8) = v;
}

// ---------------- control ----------------
__global__ void k_control(const int* __restrict__ tr, int* __restrict__ desc) {
    if (threadIdx.x != 0 || blockIdx.x != 0) return;
    int stack[140];
    int sp = 0, bp = 0, r = 0;
    for (int t = 0; t < T_; ++t) {
        int a = tr[t];
        if (a == 1) {
            if (bp < L_) { stack[sp++] = bp; bp++; }
        } else if (a == 2) {
            if (sp >= 2) {
                int right = stack[sp - 1], left = stack[sp - 2];
                sp -= 2;
                desc[2 + r] = left;
                desc[2 + RMAX + r] = right;
                stack[sp++] = -(r + 1);
                r++;
            }
        }
    }
    desc[0] = r;
    desc[1] = (sp > 0) ? stack[sp - 1] : 0;
}

// ---------------- word projection: 128x128 tile, BK=64, LDS staged ----------------
__global__ __launch_bounds__(256) void k_proj2(const unsigned short* __restrict__ sb,
                                               const unsigned short* __restrict__ wwt,
                                               const float* __restrict__ bw,
                                               unsigned short* __restrict__ hw,
                                               float* __restrict__ cw) {
    __shared__ unsigned short lA[128 * 64];   // 16KB, swizzled [row][kg^row&7]
    __shared__ unsigned short lB[128 * 64];   // 16KB
    int tid = threadIdx.x, wv = tid >> 6, lane = tid & 63;
    int lr = lane & 15, lq = lane >> 4;
    int wr = wv >> 1, wc = wv & 1;
    int rb = blockIdx.y * 128, cb = blockIdx.x * 128;
    f4v acc[4][4];
    #pragma unroll
    for (int i = 0; i < 4; ++i)
        #pragma unroll
        for (int j = 0; j < 4; ++j) acc[i][j] = (f4v){0.f, 0.f, 0.f, 0.f};

    for (int ks = 0; ks < 1024; ks += 64) {
        #pragma unroll
        for (int t = 0; t < 4; ++t) {
            int p = t * 256 + tid;
            int row = p >> 3, kgs = p & 7, kg = kgs ^ (row & 7);
            *(s8v*)(lA + (size_t)p * 8) = *(const s8v*)(sb  + (size_t)(rb + row) * 1024 + ks + kg * 8);
            *(s8v*)(lB + (size_t)p * 8) = *(const s8v*)(wwt + (size_t)(cb + row) * 1024 + ks + kg * 8);
        }
        __syncthreads();
        #pragma unroll
        for (int s = 0; s < 2; ++s) {
            int kgx = (s * 4 + lq) ^ (lr & 7);
            s8v a[4], b[4];
            #pragma unroll
            for (int i = 0; i < 4; ++i) {
                int rowa = wr * 64 + i * 16 + lr;
                int rowb = wc * 64 + i * 16 + lr;
                a[i] = *(const s8v*)(lA + (size_t)(rowa * 8 + kgx) * 8);
                b[i] = *(const s8v*)(lB + (size_t)(rowb * 8 + kgx) * 8);
            }
            #pragma unroll
            for (int i = 0; i < 4; ++i)
                #pragma unroll
                for (int j = 0; j < 4; ++j)
                    acc[i][j] = __builtin_amdgcn_mfma_f32_16x16x32_bf16(a[i], b[j], acc[i][j], 0, 0, 0);
        }
        __syncthreads();
    }
    bool isH = (cb < 1024);
    #pragma unroll
    for (int j = 0; j < 4; ++j) {
        int col = cb + wc * 64 + j * 16 + lr;
        float bias = bw[col];
        #pragma unroll
        for (int i = 0; i < 4; ++i) {
            #pragma unroll
            for (int jj = 0; jj < 4; ++jj) {
                int m = rb + wr * 64 + i * 16 + lq * 4 + jj;
                float v = acc[i][j][jj] + bias;
                if (isH) hw[(size_t)m * 1024 + col] = f2bf(v);
                else     cw[(size_t)m * 1024 + (col - 1024)] = v;
            }
        }
    }
}

// ---------------- one reduce step: 64 blocks x 512 thr, LDS chunks, K-split 4 ----------------
__global__ __launch_bounds__(512) void k_reduce2(const int* __restrict__ desc,
                                                 const unsigned short* __restrict__ hw,
                                                 const float* __restrict__ cw,
                                                 const unsigned short* __restrict__ wrtb,
                                                 const float* __restrict__ br,
                                                 unsigned short* __restrict__ nhb,
                                                 float* __restrict__ nc,
                                                 int r) {
    if (r >= desc[0]) return;
    int ls = desc[2 + r], rs = desc[2 + RMAX + r];
    __shared__ char lds[64 * KC * 2 + 80 * KC * 2];   // 144KB
    unsigned short* lA = (unsigned short*)lds;
    unsigned short* lB = (unsigned short*)(lds + 64 * KC * 2);
    float* lO = (float*)lds;                           // aliased after compute (80KB)

    int tid = threadIdx.x;
    int wv = tid >> 6, lane = tid & 63;
    int ctg = wv & 1, kq = wv >> 1;
    int lr = lane & 15, lq = lane >> 4;
    int bid = blockIdx.x;

    f4v acc[4][4];
    #pragma unroll
    for (int i = 0; i < 4; ++i)
        #pragma unroll
        for (int j = 0; j < 4; ++j) acc[i][j] = (f4v){0.f, 0.f, 0.f, 0.f};

    for (int c = 0; c < 4; ++c) {
        int srcn = (c >> 1) ? rs : ls;
        int klocal = (c & 1) * KC;
        // stage A (gathered rows, swizzled)
        #pragma unroll
        for (int t = 0; t < 8; ++t) {
            int p = t * 512 + tid;
            int row = p >> 6, kgs = p & 63;
            int kg = kgs ^ (row & 7);
            const unsigned short* base = (srcn >= 0)
                ? hw  + ((size_t)(row * L_ + srcn) << 10)
                : nhb + ((size_t)((-1 - srcn) * B_ + row) << 10);
            *(s8v*)(lA + (size_t)p * 8) = *(const s8v*)(base + klocal + kg * 8);
        }
        // stage B (pre-packed contiguous)
        const unsigned short* bsrc = wrtb + ((size_t)bid * 4 + c) * (80 * KC);
        #pragma unroll
        for (int t = 0; t < 10; ++t) {
            int p = t * 512 + tid;
            *(s8v*)(lB + (size_t)p * 8) = *(const s8v*)(bsrc + (size_t)p * 8);
        }
        __syncthreads();
        // compute my K quarter of this chunk
        #pragma unroll
        for (int kki = 0; kki < 4; ++kki) {
            int kg = kq * 16 + kki * 4 + lq;
            int kgx = kg ^ (lr & 7);
            s8v a[4];
            #pragma unroll
            for (int rf = 0; rf < 4; ++rf)
                a[rf] = *(const s8v*)(lA + (size_t)((rf * 16 + lr) * 64 + kgx) * 8);
            if (ctg == 0) {
                #pragma unroll
                for (int g = 0; g < 4; ++g) {
                    s8v b = *(const s8v*)(lB + (size_t)((g * 16 + lr) * 64 + kgx) * 8);
                    #pragma unroll
                    for (int rf = 0; rf < 4; ++rf)
                        acc[rf][g] = __builtin_amdgcn_mfma_f32_16x16x32_bf16(a[rf], b, acc[rf][g], 0, 0, 0);
                }
            } else {
                s8v b = *(const s8v*)(lB + (size_t)((64 + lr) * 64 + kgx) * 8);
                #pragma unroll
                for (int rf = 0; rf < 4; ++rf)
                    acc[rf][0] = __builtin_amdgcn_mfma_f32_16x16x32_bf16(a[rf], b, acc[rf][0], 0, 0, 0);
            }
        }
        __syncthreads();
    }
    // write K-split partials to LDS: lO[kq][gate][row64][16]
    if (ctg == 0) {
        #pragma unroll
        for (int g = 0; g < 4; ++g)
            #pragma unroll
            for (int rf = 0; rf < 4; ++rf)
                #pragma unroll
                for (int j = 0; j < 4; ++j)
                    lO[((kq * 5 + g) * 64 + rf * 16 + lq * 4 + j) * 16 + lr] = acc[rf][g][j];
    } else {
        #pragma unroll
        for (int rf = 0; rf < 4; ++rf)
            #pragma unroll
            for (int j = 0; j < 4; ++j)
                lO[((kq * 5 + 4) * 64 + rf * 16 + lq * 4 + j) * 16 + lr] = acc[rf][0][j];
    }
    __syncthreads();
    // fused TreeLSTM epilogue: 2 outputs per thread
    #pragma unroll
    for (int e = 0; e < 2; ++e) {
        int idx = e * 512 + tid;
        int m = idx >> 4, ci = idx & 15;
        int ch = bid * 16 + ci;
        float gate[5];
        #pragma unroll
        for (int g = 0; g < 5; ++g) {
            float s = 0.f;
            #pragma unroll
            for (int q = 0; q < 4; ++q) s += lO[((q * 5 + g) * 64 + m) * 16 + ci];
            gate[g] = s + br[g * 1024 + ch];
        }
        float lc = (ls >= 0) ? cw[((size_t)(m * L_ + ls) << 10) + ch]
                             : nc[((size_t)((-1 - ls) * B_ + m) << 10) + ch];
        float rc = (rs >= 0) ? cw[((size_t)(m * L_ + rs) << 10) + ch]
                             : nc[((size_t)((-1 - rs) * B_ + m) << 10) + ch];
        float cn = sigf(gate[1]) * lc + sigf(gate[2]) * rc + sigf(gate[0]) * tanhf(gate[4]);
        float hn = sigf(gate[3]) * tanhf(cn);
        size_t o = ((size_t)(r * B_ + m) << 10) + ch;
        nc[o] = cn;
        nhb[o] = f2bf(hn);
    }
}

// ---------------- final ----------------
__global__ void k_final(const int* __restrict__ desc,
                        const unsigned short* __restrict__ hw,
                        const unsigned short* __restrict__ nhb,
                        float* __restrict__ out) {
    int idx = blockIdx.x * 256 + threadIdx.x;
    if (idx >= B_ * H_) return;
    int m = idx >> 10, ch = idx & 1023;
    int fs = desc[1];
    const unsigned short* src = (fs >= 0)
        ? hw  + ((size_t)(m * L_ + fs) << 10) + ch
        : nhb + ((size_t)((-1 - fs) * B_ + m) << 10) + ch;
    out[idx] = bf2f(*src);
}

extern "C" void kernel_launch(void* const* d_in, const int* in_sizes, int n_in,
                              void* d_out, int out_size, void* d_ws, size_t ws_size,
                              hipStream_t stream) {
    const float* sentence = (const float*)d_in[0];
    const int*   trans    = (const int*)d_in[1];
    const float* Ww       = (const float*)d_in[2];
    const float* bw       = (const float*)d_in[3];
    const float* Wr       = (const float*)d_in[4];
    const float* br       = (const float*)d_in[5];
    float* out = (float*)d_out;

    char* w = (char*)d_ws;
    size_t off = 0;
    unsigned short* Wrt  = (unsigned short*)(w + off); off += (size_t)5120 * 2048 * 2;   // 21.0 MB
    unsigned short* WrtB = (unsigned short*)(w + off); off += (size_t)5120 * 2048 * 2;   // 21.0 MB
    unsigned short* Wwt  = (unsigned short*)(w + off); off += (size_t)2048 * 1024 * 2;   //  4.2 MB
    unsigned short* sb   = (unsigned short*)(w + off); off += (size_t)8192 * 1024 * 2;   // 16.8 MB
    unsigned short* hw   = (unsigned short*)(w + off); off += (size_t)8192 * 1024 * 2;   // 16.8 MB
    float*          cw   = (float*)(w + off);          off += (size_t)8192 * 1024 * 4;   // 33.6 MB
    unsigned short* nhb  = (unsigned short*)(w + off); off += (size_t)RMAX * 64 * 1024 * 2; // 16.6 MB
    float*          nc   = (float*)(w + off);          off += (size_t)RMAX * 64 * 1024 * 4; // 33.3 MB
    int*            desc = (int*)(w + off);            off += 1024;

    {
        long n4 = (long)8192 * 1024 / 4;
        k_cvt_bf16<<<dim3((unsigned)((n4 + 255) / 256)), dim3(256), 0, stream>>>(sentence, sb, n4);
    }
    k_transpose_bf16<<<dim3(2048 / 32, 1024 / 32), dim3(32, 8), 0, stream>>>(Ww, Wwt, 1024, 2048);
    k_transpose_bf16<<<dim3(5120 / 32, 2048 / 32), dim3(32, 8), 0, stream>>>(Wr, Wrt, 2048, 5120);
    k_pack_wr<<<dim3(5120), dim3(256), 0, stream>>>(Wrt, WrtB);
    k_control<<<dim3(1), dim3(1), 0, stream>>>(trans, desc);
    k_proj2<<<dim3(16, 64), dim3(256), 0, stream>>>(sb, Wwt, bw, hw, cw);
    for (int r = 0; r < RMAX; ++r)
        k_reduce2<<<dim3(64), dim3(512), 0, stream>>>(desc, hw, cw, WrtB, br, nhb, nc, r);
    k_final<<<dim3((64 * 1024 + 255) / 256), dim3(256), 0, stream>>>(desc, hw, nhb, out);
}